// Round 10
// baseline (596.109 us; speedup 1.0000x reference)
//
#include <hip/hip_runtime.h>
#include <math.h>

#define Bq 8
#define Tq 4096
#define Dq 512
#define Qn 4
#define Kk 1024
#define OWn 2048
#define NROWS (Bq*Tq)

#define QO_OFF (Bq*OWn*Dq)
#define IDX_OFF (QO_OFF + Bq*Tq*Dq)
#define LOSS_OFF (IDX_OFF + Qn*NROWS)

typedef __bf16 bf16x8 __attribute__((ext_vector_type(8)));
typedef _Float16 f16x8 __attribute__((ext_vector_type(8)));
typedef float f32x16 __attribute__((ext_vector_type(16)));
typedef float f32x4 __attribute__((ext_vector_type(4)));

__device__ __forceinline__ unsigned pack2h(_Float16 a, _Float16 b) {
  return (unsigned)__builtin_bit_cast(unsigned short, a)
       | ((unsigned)__builtin_bit_cast(unsigned short, b) << 16);
}

// ============ prep: codebook norms + fragment-ready fp16 codebook ============
__global__ __launch_bounds__(256) void prep_cb(const float* __restrict__ cb,
                                               float* __restrict__ cbnorm,
                                               _Float16* __restrict__ cbf,
                                               float* __restrict__ lacc) {
  int w = threadIdx.x >> 6, lane = threadIdx.x & 63;
  int row = blockIdx.x * 4 + w;                 // 0..4095 = q*1024 + k
  int q = row >> 10, k = row & 1023;
  const f32x4* c4 = (const f32x4*)(cb + (size_t)row * Dq);
  f32x4 v0 = c4[lane * 2], v1 = c4[lane * 2 + 1];
  float s = v0.x*v0.x + v0.y*v0.y + v0.z*v0.z + v0.w*v0.w
          + v1.x*v1.x + v1.y*v1.y + v1.z*v1.z + v1.w*v1.w;
  f16x8 bv;
  bv[0]=(_Float16)v0.x; bv[1]=(_Float16)v0.y; bv[2]=(_Float16)v0.z; bv[3]=(_Float16)v0.w;
  bv[4]=(_Float16)v1.x; bv[5]=(_Float16)v1.y; bv[6]=(_Float16)v1.z; bv[7]=(_Float16)v1.w;
  // fragment layout: [blk=k>>5][ds=lane>>1][hs=lane&1][l31=k&31][8]
  int ds = lane >> 1, hs = lane & 1;
  size_t off = ((size_t)((k >> 5) * 32 + ds) * 2 + hs) * 256 + (k & 31) * 8;
  *(f16x8*)(cbf + (size_t)q * (Kk * Dq) + off) = bv;
#pragma unroll
  for (int off2 = 32; off2; off2 >>= 1) s += __shfl_down(s, off2);
  if (lane == 0) cbnorm[row] = s;
  if (blockIdx.x == 0 && threadIdx.x == 0) *lacc = 0.f;
}

__global__ __launch_bounds__(256) void prep_cmax(const float* __restrict__ cbnorm,
                                                 float* __restrict__ cmax) {
  int w = threadIdx.x >> 6, lane = threadIdx.x & 63;
  float m = 0.f;
#pragma unroll
  for (int j = 0; j < 16; ++j) m = fmaxf(m, cbnorm[w * Kk + lane * 16 + j]);
#pragma unroll
  for (int off = 32; off; off >>= 1) m = fmaxf(m, __shfl_down(m, off));
  if (lane == 0) cmax[w] = sqrtf(m);
}

// ============ prep: fragment-ready bf16 conv weights ============
__global__ __launch_bounds__(256) void prep_wb(const float* __restrict__ w,
                                               __bf16* __restrict__ wb) {
  int g = blockIdx.x * 256 + threadIdx.x;       // 0..163839
  int l31 = g & 31, hs = (g >> 5) & 1, c32 = (g >> 6) & 15, s = g >> 10;
  int kw = s >> 5, ci16 = s & 31;
  int ci = ci16 * 16 + hs * 8;
  int co = c32 * 32 + l31;
  bf16x8 bv;
#pragma unroll
  for (int e = 0; e < 8; ++e)
    bv[e] = (__bf16)w[(size_t)(kw * Dq + ci + e) * Dq + co];
  *(bf16x8*)(wb + (size_t)g * 8) = bv;
}

// ============ fully-fused residual VQ: 4 steps, residual in registers ========
// 1024 thr = 16 waves; 64 rows/block. Wave w: residual rows w*4..w*4+3;
// screen split 8 col-groups x 2 row-tiles: cg=w&7 (128 cols), rg=w>>3 (32 rows).
// Per-thread state ~110 VGPR -> fits forced 128 cap, NO spill. grid 512.
__global__ __launch_bounds__(1024, 1) void vq_all(
    const float* __restrict__ x, float* __restrict__ qo,
    const _Float16* __restrict__ cbf, const float* __restrict__ cb,
    const float* __restrict__ cbnorm, const float* __restrict__ cmax,
    float* __restrict__ idxo, float* __restrict__ lacc) {
  __shared__ _Float16 rh[64 * 512];             // 64KB swizzled residual tile
  __shared__ unsigned redB[64 * 8];
  __shared__ float rnorm_l[64];
  __shared__ float thrL[64];
  __shared__ int rowcount[64];
  __shared__ unsigned short rowlist[64 * 32];

  const int tid = threadIdx.x;
  const int w = tid >> 6, lane = tid & 63, l31 = lane & 31, hs = lane >> 5;
  const int row0g = blockIdx.x * 64;
  char* rhc = (char*)rh;

  // residual state: wave w rows w*4+rr, lane holds d = lane*8..lane*8+7
  f32x4 r0[4], r1[4];
#pragma unroll
  for (int rr = 0; rr < 4; ++rr) {
    size_t gb = (size_t)(row0g + w * 4 + rr) * Dq + lane * 8;
    r0[rr] = *(const f32x4*)(x + gb);
    r1[rr] = *(const f32x4*)(x + gb + 4);
  }
  float lsum = 0.f;

#pragma unroll 1
  for (int qi = 0; qi < Qn; ++qi) {
    const _Float16* cbf_q = cbf + (size_t)qi * (Kk * Dq);
    const float*    cb_q  = cb  + (size_t)qi * (Kk * Dq);
    const float*    cbn_q = cbnorm + qi * Kk;

    // ---- stage fp16 residual to LDS + per-row ||r||^2 ----
#pragma unroll
    for (int rr = 0; rr < 4; ++rr) {
      int row = w * 4 + rr;
      f16x8 bv;
      bv[0]=(_Float16)r0[rr].x; bv[1]=(_Float16)r0[rr].y;
      bv[2]=(_Float16)r0[rr].z; bv[3]=(_Float16)r0[rr].w;
      bv[4]=(_Float16)r1[rr].x; bv[5]=(_Float16)r1[rr].y;
      bv[6]=(_Float16)r1[rr].z; bv[7]=(_Float16)r1[rr].w;
      *(f16x8*)(rhc + ((row * 1024 + lane * 16) ^ ((row & 7) << 4))) = bv;
      float rn = r0[rr].x*r0[rr].x + r0[rr].y*r0[rr].y + r0[rr].z*r0[rr].z + r0[rr].w*r0[rr].w
               + r1[rr].x*r1[rr].x + r1[rr].y*r1[rr].y + r1[rr].z*r1[rr].z + r1[rr].w*r1[rr].w;
#pragma unroll
      for (int off = 1; off < 64; off <<= 1) rn += __shfl_xor(rn, off);
      if (lane == 0) rnorm_l[row] = rn;
    }
    __syncthreads();                            // A: rh ready

    // ---- MFMA screen: wave w = (cg,rg): cols cg*128..+127 x rows rg*32..+31 --
    unsigned ps[4][8];                          // [ct][j] packed fp16 scores
    const int cg = w & 7, rg = w >> 3;
    const int ab0 = (rg * 32 + l31) * 1024 + hs * 16;
    const int asw = (l31 & 7) << 4;
#pragma unroll
    for (int p = 0; p < 2; ++p) {
      const int ct0 = 2 * p, ct1 = 2 * p + 1;
      const _Float16* bp0 = cbf_q + (size_t)(cg * 4 + ct0) * 16384 + hs * 256 + l31 * 8;
      const _Float16* bp1 = cbf_q + (size_t)(cg * 4 + ct1) * 16384 + hs * 256 + l31 * 8;
      f32x16 accA, accB;
#pragma unroll
      for (int i = 0; i < 16; ++i) { accA[i] = 0.f; accB[i] = 0.f; }
#pragma unroll 8
      for (int ds = 0; ds < 32; ++ds) {
        f16x8 a  = *(const f16x8*)(rhc + ((ab0 + ds * 32) ^ asw));
        f16x8 b0 = *(const f16x8*)(bp0 + ds * 512);
        f16x8 b1 = *(const f16x8*)(bp1 + ds * 512);
        accA = __builtin_amdgcn_mfma_f32_32x32x16_f16(a, b0, accA, 0, 0, 0);
        accB = __builtin_amdgcn_mfma_f32_32x32x16_f16(a, b1, accB, 0, 0, 0);
      }
      const float cn0 = cbn_q[cg * 128 + ct0 * 32 + l31];
      const float cn1 = cbn_q[cg * 128 + ct1 * 32 + l31];
#pragma unroll
      for (int j = 0; j < 8; ++j) {
        ps[ct0][j] = pack2h((_Float16)(cn0 - 2.f * accA[2*j]), (_Float16)(cn0 - 2.f * accA[2*j+1]));
        ps[ct1][j] = pack2h((_Float16)(cn1 - 2.f * accB[2*j]), (_Float16)(cn1 - 2.f * accB[2*j+1]));
      }
    }

    // ---- per-row packed (score,col) argmin across this wave's 128 cols ----
    {
      unsigned pk[16];
#pragma unroll
      for (int i = 0; i < 16; ++i) {
        pk[i] = 0xFFFFFFFFu;
#pragma unroll
        for (int ct = 0; ct < 4; ++ct) {
          unsigned col = (unsigned)(cg * 128 + ct * 32 + l31);
          unsigned u = (ps[ct][i >> 1] >> ((i & 1) * 16)) & 0xFFFFu;
          unsigned key = (u & 0x8000u) ? (u ^ 0xFFFFu) : (u | 0x8000u);
          unsigned pkc = (key << 10) | col;
          if (pkc < pk[i]) pk[i] = pkc;
        }
#pragma unroll
        for (int off = 1; off <= 16; off <<= 1) {
          unsigned t = __shfl_xor(pk[i], off);
          if (t < pk[i]) pk[i] = t;
        }
      }
      if (l31 == 0) {
#pragma unroll
        for (int i = 0; i < 16; ++i) {
          int rit = rg * 32 + (i & 3) + 8 * (i >> 2) + 4 * hs;
          redB[rit * 8 + cg] = pk[i];
        }
      }
    }
    __syncthreads();                            // B: redB ready

    if (tid < 64) {
      unsigned mb = redB[tid * 8];
#pragma unroll
      for (int j = 1; j < 8; ++j) {
        unsigned v = redB[tid * 8 + j];
        if (v < mb) mb = v;
      }
      unsigned key = (mb >> 10) & 0xFFFFu;
      unsigned ub = (key & 0x8000u) ? (key ^ 0x8000u) : (key ^ 0xFFFFu);
      float mstar = (float)__builtin_bit_cast(_Float16, (unsigned short)ub);
      float rn = sqrtf(rnorm_l[tid]);
      float cm = cmax[qi];
      // certified fp16 window: 2*(2u*2*rn*cm) + pack slack
      thrL[tid] = mstar + 0.005f * rn * cm + 0.001f * fabsf(mstar) + 0.3f;
      rowcount[tid] = 0;
    }
    __syncthreads();                            // C: thr ready

    // ---- candidate scan from register scores ----
#pragma unroll
    for (int i = 0; i < 16; ++i) {
      int rit = rg * 32 + (i & 3) + 8 * (i >> 2) + 4 * hs;
      float t = thrL[rit];
#pragma unroll
      for (int ct = 0; ct < 4; ++ct) {
        unsigned col = (unsigned)(cg * 128 + ct * 32 + l31);
        unsigned u = (ps[ct][i >> 1] >> ((i & 1) * 16)) & 0xFFFFu;
        float s = (float)__builtin_bit_cast(_Float16, (unsigned short)u);
        if (s <= t) {
          int p = atomicAdd(&rowcount[rit], 1);
          if (p < 32) rowlist[rit * 32 + p] = (unsigned short)col;
        }
      }
    }
    __syncthreads();                            // D: rowlist ready

    // ---- exact f32 rescore + register residual update ----
#pragma unroll
    for (int rr = 0; rr < 4; ++rr) {
      int row = w * 4 + rr;
      int cnt = rowcount[row];
      int total = (cnt > 32) ? Kk : cnt;
      float bs = 3.4028235e38f; int bk = 1 << 30;
      for (int ci2 = 0; ci2 < total; ++ci2) {
        int k = (cnt > 32) ? ci2 : (int)rowlist[row * 32 + ci2];
        const f32x4* crow = (const f32x4*)(cb_q + ((size_t)k << 9)) + lane * 2;
        f32x4 c0 = crow[0], c1 = crow[1];
        float dot = 0.f;
        dot = fmaf(r0[rr].x, c0.x, dot); dot = fmaf(r0[rr].y, c0.y, dot);
        dot = fmaf(r0[rr].z, c0.z, dot); dot = fmaf(r0[rr].w, c0.w, dot);
        dot = fmaf(r1[rr].x, c1.x, dot); dot = fmaf(r1[rr].y, c1.y, dot);
        dot = fmaf(r1[rr].z, c1.z, dot); dot = fmaf(r1[rr].w, c1.w, dot);
#pragma unroll
        for (int off = 1; off < 64; off <<= 1) dot += __shfl_xor(dot, off);
        float sc = cbn_q[k] - 2.f * dot;
        if (sc < bs || (sc == bs && k < bk)) { bs = sc; bk = k; }
      }
      if (lane == 0) idxo[(size_t)qi * NROWS + row0g + row] = (float)bk;
      const f32x4* crow = (const f32x4*)(cb_q + ((size_t)bk << 9)) + lane * 2;
      f32x4 c0 = crow[0], c1 = crow[1];
      r0[rr].x -= c0.x; r0[rr].y -= c0.y; r0[rr].z -= c0.z; r0[rr].w -= c0.w;
      r1[rr].x -= c1.x; r1[rr].y -= c1.y; r1[rr].z -= c1.z; r1[rr].w -= c1.w;
      lsum += r0[rr].x*r0[rr].x + r0[rr].y*r0[rr].y + r0[rr].z*r0[rr].z + r0[rr].w*r0[rr].w
            + r1[rr].x*r1[rr].x + r1[rr].y*r1[rr].y + r1[rr].z*r1[rr].z + r1[rr].w*r1[rr].w;
    }
    __syncthreads();                            // E: step done
  }

  // ---- write quantized_out = x - r_final ----
#pragma unroll
  for (int rr = 0; rr < 4; ++rr) {
    size_t gb = (size_t)(row0g + w * 4 + rr) * Dq + lane * 8;
    f32x4 xv0 = *(const f32x4*)(x + gb), xv1 = *(const f32x4*)(x + gb + 4);
    f32x4 o0, o1;
    o0.x = xv0.x - r0[rr].x; o0.y = xv0.y - r0[rr].y;
    o0.z = xv0.z - r0[rr].z; o0.w = xv0.w - r0[rr].w;
    o1.x = xv1.x - r1[rr].x; o1.y = xv1.y - r1[rr].y;
    o1.z = xv1.z - r1[rr].z; o1.w = xv1.w - r1[rr].w;
    *(f32x4*)(qo + gb) = o0;
    *(f32x4*)(qo + gb + 4) = o1;
  }
#pragma unroll
  for (int off = 1; off < 64; off <<= 1) lsum += __shfl_xor(lsum, off);
  if (lane == 0) atomicAdd(lacc, lsum);
}

// ============ conv1d stride2 SAME via bf16 MFMA + exact GELU ============
__global__ __launch_bounds__(512, 2) void conv_mfma(const float* __restrict__ qo,
                                                    const __bf16* __restrict__ wb,
                                                    float* __restrict__ y) {
  __shared__ char As[259 * 128];                // 259 input rows x 64 ci bf16
  const int tid = threadIdx.x;
  const int w = tid >> 6, lane = tid & 63, l31 = lane & 31, hs = lane >> 5;
  const int rowblk = blockIdx.x, coblk = blockIdx.y;
  const int n = rowblk >> 4;
  const int o0 = (rowblk & 15) * 128;
  const int t0 = 2 * o0 - 1;
  const int c32g = coblk * 8 + w;

  f32x16 acc[4];
#pragma unroll
  for (int rt = 0; rt < 4; ++rt)
#pragma unroll
    for (int i = 0; i < 16; ++i) acc[rt][i] = 0.f;

  for (int ct8 = 0; ct8 < 8; ++ct8) {
    __syncthreads();
    for (int s = tid; s < 2072; s += 512) {
      int irow = s >> 3, cg = s & 7;
      int t = t0 + irow;
      bf16x8 bv;
      if (t >= 0 && t < Tq) {
        const float* src = qo + ((size_t)(n * Tq + t)) * Dq + ct8 * 64 + cg * 8;
        f32x4 v0 = *(const f32x4*)(src), v1 = *(const f32x4*)(src + 4);
        bv[0]=(__bf16)v0.x; bv[1]=(__bf16)v0.y; bv[2]=(__bf16)v0.z; bv[3]=(__bf16)v0.w;
        bv[4]=(__bf16)v1.x; bv[5]=(__bf16)v1.y; bv[6]=(__bf16)v1.z; bv[7]=(__bf16)v1.w;
      } else {
#pragma unroll
        for (int e = 0; e < 8; ++e) bv[e] = (__bf16)0.f;
      }
      *(bf16x8*)(As + ((irow * 128 + cg * 16) ^ (((irow >> 1) & 7) << 4))) = bv;
    }
    __syncthreads();
#pragma unroll
    for (int kw = 0; kw < 5; ++kw) {
#pragma unroll
      for (int ks = 0; ks < 4; ++ks) {
        int s16 = kw * 32 + ct8 * 4 + ks;
        bf16x8 b = *(const bf16x8*)(wb + ((size_t)(s16 * 16 + c32g) * 2 + hs) * 256 + l31 * 8);
#pragma unroll
        for (int rt = 0; rt < 4; ++rt) {
          int ir = 2 * (rt * 32 + l31) + kw;
          bf16x8 a = *(const bf16x8*)(As + ((ir * 128 + ks * 32 + hs * 16) ^ (((ir >> 1) & 7) << 4)));
          acc[rt] = __builtin_amdgcn_mfma_f32_32x32x16_bf16(a, b, acc[rt], 0, 0, 0);
        }
      }
    }
  }
  const int co = coblk * 256 + w * 32 + l31;
#pragma unroll
  for (int rt = 0; rt < 4; ++rt)
#pragma unroll
    for (int i = 0; i < 16; ++i) {
      int orow = rt * 32 + (i & 3) + 8 * (i >> 2) + 4 * hs;
      float v = acc[rt][i];
      float g = 0.5f * v * (1.f + erff(v * 0.70710678118654752f));
      y[((size_t)(n * OWn + o0 + orow)) * Dq + co] = g;
    }
}

__global__ void loss_final(const float* __restrict__ lacc, float* __restrict__ out) {
  out[0] = 0.25f * lacc[0] / 16777216.0f;
}

extern "C" void kernel_launch(void* const* d_in, const int* in_sizes, int n_in,
                              void* d_out, int out_size, void* d_ws, size_t ws_size,
                              hipStream_t stream) {
  const float* x  = (const float*)d_in[0];
  const float* cb = (const float*)d_in[1];
  const float* cw = (const float*)d_in[2];
  float* out = (float*)d_out;
  float* y    = out;
  float* qo   = out + QO_OFF;
  float* idxo = out + IDX_OFF;
  float* losso = out + LOSS_OFF;

  float* fws    = (float*)d_ws;
  float* lacc   = fws;                // 1
  float* cmax   = fws + 8;            // 4
  float* cbnorm = fws + 16;           // 4096
  _Float16* cbf = (_Float16*)((char*)d_ws + (32 << 10));    // 4 MB
  __bf16* wb  = (__bf16*)((char*)d_ws + (8 << 20));         // 2.62 MB

  prep_cb<<<1024, 256, 0, stream>>>(cb, cbnorm, cbf, lacc);
  prep_cmax<<<1, 256, 0, stream>>>(cbnorm, cmax);
  prep_wb<<<640, 256, 0, stream>>>(cw, wb);

  vq_all<<<512, 1024, 0, stream>>>(x, qo, cbf, cb, cbnorm, cmax, idxo, lacc);

  conv_mfma<<<dim3(128, 2), 512, 0, stream>>>(qo, wb, y);
  loss_final<<<1, 1, 0, stream>>>(lacc, losso);
}

// Round 13
// 477.007 us; speedup vs baseline: 1.2497x; 1.2497x over previous
//
#include <hip/hip_runtime.h>
#include <math.h>

#define Bq 8
#define Tq 4096
#define Dq 512
#define Qn 4
#define Kk 1024
#define OWn 2048
#define NROWS (Bq*Tq)

#define QO_OFF (Bq*OWn*Dq)
#define IDX_OFF (QO_OFF + Bq*Tq*Dq)
#define LOSS_OFF (IDX_OFF + Qn*NROWS)

typedef __bf16 bf16x8 __attribute__((ext_vector_type(8)));
typedef _Float16 f16x8 __attribute__((ext_vector_type(8)));
typedef float f32x16 __attribute__((ext_vector_type(16)));
typedef float f32x4 __attribute__((ext_vector_type(4)));

__device__ __forceinline__ unsigned pack2h(_Float16 a, _Float16 b) {
  return (unsigned)__builtin_bit_cast(unsigned short, a)
       | ((unsigned)__builtin_bit_cast(unsigned short, b) << 16);
}

// ============ prep: codebook norms + fragment-ready fp16 codebook ============
__global__ __launch_bounds__(256) void prep_cb(const float* __restrict__ cb,
                                               float* __restrict__ cbnorm,
                                               _Float16* __restrict__ cbf,
                                               float* __restrict__ lacc) {
  int w = threadIdx.x >> 6, lane = threadIdx.x & 63;
  int row = blockIdx.x * 4 + w;                 // 0..4095 = q*1024 + k
  int q = row >> 10, k = row & 1023;
  const f32x4* c4 = (const f32x4*)(cb + (size_t)row * Dq);
  f32x4 v0 = c4[lane * 2], v1 = c4[lane * 2 + 1];
  float s = v0.x*v0.x + v0.y*v0.y + v0.z*v0.z + v0.w*v0.w
          + v1.x*v1.x + v1.y*v1.y + v1.z*v1.z + v1.w*v1.w;
  f16x8 bv;
  bv[0]=(_Float16)v0.x; bv[1]=(_Float16)v0.y; bv[2]=(_Float16)v0.z; bv[3]=(_Float16)v0.w;
  bv[4]=(_Float16)v1.x; bv[5]=(_Float16)v1.y; bv[6]=(_Float16)v1.z; bv[7]=(_Float16)v1.w;
  // fragment layout: [blk=k>>5][ds=lane>>1][hs=lane&1][l31=k&31][8]
  int ds = lane >> 1, hs = lane & 1;
  size_t off = ((size_t)((k >> 5) * 32 + ds) * 2 + hs) * 256 + (k & 31) * 8;
  *(f16x8*)(cbf + (size_t)q * (Kk * Dq) + off) = bv;
#pragma unroll
  for (int off2 = 32; off2; off2 >>= 1) s += __shfl_down(s, off2);
  if (lane == 0) cbnorm[row] = s;
  if (blockIdx.x == 0 && threadIdx.x == 0) *lacc = 0.f;
}

__global__ __launch_bounds__(256) void prep_cmax(const float* __restrict__ cbnorm,
                                                 float* __restrict__ cmax) {
  int w = threadIdx.x >> 6, lane = threadIdx.x & 63;
  float m = 0.f;
#pragma unroll
  for (int j = 0; j < 16; ++j) m = fmaxf(m, cbnorm[w * Kk + lane * 16 + j]);
#pragma unroll
  for (int off = 32; off; off >>= 1) m = fmaxf(m, __shfl_down(m, off));
  if (lane == 0) cmax[w] = sqrtf(m);
}

// ============ prep: fragment-ready bf16 conv weights ============
__global__ __launch_bounds__(256) void prep_wb(const float* __restrict__ w,
                                               __bf16* __restrict__ wb) {
  int g = blockIdx.x * 256 + threadIdx.x;       // 0..163839
  int l31 = g & 31, hs = (g >> 5) & 1, c32 = (g >> 6) & 15, s = g >> 10;
  int kw = s >> 5, ci16 = s & 31;
  int ci = ci16 * 16 + hs * 8;
  int co = c32 * 32 + l31;
  bf16x8 bv;
#pragma unroll
  for (int e = 0; e < 8; ++e)
    bv[e] = (__bf16)w[(size_t)(kw * Dq + ci + e) * Dq + co];
  *(bf16x8*)(wb + (size_t)g * 8) = bv;
}

// ============ fully-fused residual VQ: 4 steps, residual in registers ========
// 512 thr = 8 waves; 64 rows/block (wave w: residual rows w*8..w*8+7,
// screen cols w*128..+127 x all 64 rows). grid 512.  [r9 structure, green]
__global__ __launch_bounds__(512, 1) void vq_all(
    const float* __restrict__ x, float* __restrict__ qo,
    const _Float16* __restrict__ cbf, const float* __restrict__ cb,
    const float* __restrict__ cbnorm, const float* __restrict__ cmax,
    float* __restrict__ idxo, float* __restrict__ lacc) {
  __shared__ _Float16 rh[64 * 512];             // 64KB swizzled residual tile
  __shared__ unsigned redB[64 * 8];
  __shared__ float rnorm_l[64];
  __shared__ float thrL[64];
  __shared__ int rowcount[64];
  __shared__ unsigned short rowlist[64 * 32];

  const int tid = threadIdx.x;
  const int w = tid >> 6, lane = tid & 63, l31 = lane & 31, hs = lane >> 5;
  const int row0g = blockIdx.x * 64;
  char* rhc = (char*)rh;

  // residual state: wave w rows w*8+rr, lane holds d = lane*8..lane*8+7
  f32x4 r0[8], r1[8];
#pragma unroll
  for (int rr = 0; rr < 8; ++rr) {
    size_t gb = (size_t)(row0g + w * 8 + rr) * Dq + lane * 8;
    r0[rr] = *(const f32x4*)(x + gb);
    r1[rr] = *(const f32x4*)(x + gb + 4);
  }
  float lsum = 0.f;

#pragma unroll 1
  for (int qi = 0; qi < Qn; ++qi) {
    const _Float16* cbf_q = cbf + (size_t)qi * (Kk * Dq);
    const float*    cb_q  = cb  + (size_t)qi * (Kk * Dq);
    const float*    cbn_q = cbnorm + qi * Kk;

    // ---- stage fp16 residual to LDS + per-row ||r||^2 ----
#pragma unroll
    for (int rr = 0; rr < 8; ++rr) {
      int row = w * 8 + rr;
      f16x8 bv;
      bv[0]=(_Float16)r0[rr].x; bv[1]=(_Float16)r0[rr].y;
      bv[2]=(_Float16)r0[rr].z; bv[3]=(_Float16)r0[rr].w;
      bv[4]=(_Float16)r1[rr].x; bv[5]=(_Float16)r1[rr].y;
      bv[6]=(_Float16)r1[rr].z; bv[7]=(_Float16)r1[rr].w;
      *(f16x8*)(rhc + ((row * 1024 + lane * 16) ^ ((row & 7) << 4))) = bv;
      float rn = r0[rr].x*r0[rr].x + r0[rr].y*r0[rr].y + r0[rr].z*r0[rr].z + r0[rr].w*r0[rr].w
               + r1[rr].x*r1[rr].x + r1[rr].y*r1[rr].y + r1[rr].z*r1[rr].z + r1[rr].w*r1[rr].w;
#pragma unroll
      for (int off = 1; off < 64; off <<= 1) rn += __shfl_xor(rn, off);
      if (lane == 0) rnorm_l[row] = rn;
    }
    __syncthreads();                            // A: rh ready

    // ---- MFMA screen: wave w owns cols w*128..+127; both 32-row tiles;
    //      B fragments reused across row tiles; scores packed fp16 in regs ----
    unsigned psA[4][8], psB[4][8];              // [ct][j]: rows tile0 / tile1
    const int ab0 = l31 * 1024 + hs * 16;
    const int asw = (l31 & 7) << 4;
#pragma unroll
    for (int p = 0; p < 2; ++p) {
      const int ct0 = 2 * p, ct1 = 2 * p + 1;
      const _Float16* bp0 = cbf_q + (size_t)(w * 4 + ct0) * 16384 + hs * 256 + l31 * 8;
      const _Float16* bp1 = cbf_q + (size_t)(w * 4 + ct1) * 16384 + hs * 256 + l31 * 8;
      f32x16 a00, a01, a10, a11;
#pragma unroll
      for (int i = 0; i < 16; ++i) { a00[i]=0.f; a01[i]=0.f; a10[i]=0.f; a11[i]=0.f; }
#pragma unroll 8
      for (int ds = 0; ds < 32; ++ds) {
        f16x8 a0 = *(const f16x8*)(rhc + ((ab0 + ds * 32) ^ asw));
        f16x8 a1 = *(const f16x8*)(rhc + ((ab0 + 32 * 1024 + ds * 32) ^ asw));
        f16x8 b0 = *(const f16x8*)(bp0 + ds * 512);
        f16x8 b1 = *(const f16x8*)(bp1 + ds * 512);
        a00 = __builtin_amdgcn_mfma_f32_32x32x16_f16(a0, b0, a00, 0, 0, 0);
        a01 = __builtin_amdgcn_mfma_f32_32x32x16_f16(a0, b1, a01, 0, 0, 0);
        a10 = __builtin_amdgcn_mfma_f32_32x32x16_f16(a1, b0, a10, 0, 0, 0);
        a11 = __builtin_amdgcn_mfma_f32_32x32x16_f16(a1, b1, a11, 0, 0, 0);
      }
      const float cn0 = cbn_q[w * 128 + ct0 * 32 + l31];
      const float cn1 = cbn_q[w * 128 + ct1 * 32 + l31];
#pragma unroll
      for (int j = 0; j < 8; ++j) {
        psA[ct0][j] = pack2h((_Float16)(cn0 - 2.f * a00[2*j]), (_Float16)(cn0 - 2.f * a00[2*j+1]));
        psA[ct1][j] = pack2h((_Float16)(cn1 - 2.f * a01[2*j]), (_Float16)(cn1 - 2.f * a01[2*j+1]));
        psB[ct0][j] = pack2h((_Float16)(cn0 - 2.f * a10[2*j]), (_Float16)(cn0 - 2.f * a10[2*j+1]));
        psB[ct1][j] = pack2h((_Float16)(cn1 - 2.f * a11[2*j]), (_Float16)(cn1 - 2.f * a11[2*j+1]));
      }
    }

    // ---- per-row packed (score,col) argmin across this wave's 128 cols ----
#pragma unroll
    for (int rt = 0; rt < 2; ++rt) {
      unsigned pk[16];
#pragma unroll
      for (int i = 0; i < 16; ++i) {
        pk[i] = 0xFFFFFFFFu;
#pragma unroll
        for (int ct = 0; ct < 4; ++ct) {
          unsigned col = (unsigned)(w * 128 + ct * 32 + l31);
          unsigned u = ((rt == 0 ? psA[ct][i >> 1] : psB[ct][i >> 1]) >> ((i & 1) * 16)) & 0xFFFFu;
          unsigned key = (u & 0x8000u) ? (u ^ 0xFFFFu) : (u | 0x8000u);
          unsigned pkc = (key << 10) | col;
          if (pkc < pk[i]) pk[i] = pkc;
        }
#pragma unroll
        for (int off = 1; off <= 16; off <<= 1) {
          unsigned t = __shfl_xor(pk[i], off);
          if (t < pk[i]) pk[i] = t;
        }
      }
      if (l31 == 0) {
#pragma unroll
        for (int i = 0; i < 16; ++i) {
          int rit = rt * 32 + (i & 3) + 8 * (i >> 2) + 4 * hs;
          redB[rit * 8 + w] = pk[i];
        }
      }
    }
    __syncthreads();                            // B: redB ready

    if (tid < 64) {
      unsigned mb = redB[tid * 8];
#pragma unroll
      for (int j = 1; j < 8; ++j) {
        unsigned v = redB[tid * 8 + j];
        if (v < mb) mb = v;
      }
      unsigned key = (mb >> 10) & 0xFFFFu;
      unsigned ub = (key & 0x8000u) ? (key ^ 0x8000u) : (key ^ 0xFFFFu);
      float mstar = (float)__builtin_bit_cast(_Float16, (unsigned short)ub);
      float rn = sqrtf(rnorm_l[tid]);
      float cm = cmax[qi];
      // certified fp16 window: 2*(2u*2*rn*cm) + pack slack
      thrL[tid] = mstar + 0.005f * rn * cm + 0.001f * fabsf(mstar) + 0.3f;
      rowcount[tid] = 0;
    }
    __syncthreads();                            // C: thr ready

    // ---- candidate scan from register scores ----
#pragma unroll
    for (int rt = 0; rt < 2; ++rt) {
#pragma unroll
      for (int i = 0; i < 16; ++i) {
        int rit = rt * 32 + (i & 3) + 8 * (i >> 2) + 4 * hs;
        float t = thrL[rit];
#pragma unroll
        for (int ct = 0; ct < 4; ++ct) {
          unsigned col = (unsigned)(w * 128 + ct * 32 + l31);
          unsigned u = ((rt == 0 ? psA[ct][i >> 1] : psB[ct][i >> 1]) >> ((i & 1) * 16)) & 0xFFFFu;
          float s = (float)__builtin_bit_cast(_Float16, (unsigned short)u);
          if (s <= t) {
            int p = atomicAdd(&rowcount[rit], 1);
            if (p < 32) rowlist[rit * 32 + p] = (unsigned short)col;
          }
        }
      }
    }
    __syncthreads();                            // D: rowlist ready

    // ---- exact f32 rescore + register residual update ----
    // cnt==1 shortcut: r9 (rescore-all, passing) proves the list always
    // contains the true argmin when cnt<=32; a 1-entry list IS the argmin.
#pragma unroll
    for (int rr = 0; rr < 8; ++rr) {
      int row = w * 8 + rr;
      int cnt = rowcount[row];
      int bk;
      if (cnt == 1) {
        bk = (int)rowlist[row * 32];
      } else {
        int total = (cnt > 32) ? Kk : cnt;
        float bs = 3.4028235e38f; bk = 1 << 30;
        for (int ci2 = 0; ci2 < total; ++ci2) {
          int k = (cnt > 32) ? ci2 : (int)rowlist[row * 32 + ci2];
          const f32x4* crow = (const f32x4*)(cb_q + ((size_t)k << 9)) + lane * 2;
          f32x4 c0 = crow[0], c1 = crow[1];
          float dot = 0.f;
          dot = fmaf(r0[rr].x, c0.x, dot); dot = fmaf(r0[rr].y, c0.y, dot);
          dot = fmaf(r0[rr].z, c0.z, dot); dot = fmaf(r0[rr].w, c0.w, dot);
          dot = fmaf(r1[rr].x, c1.x, dot); dot = fmaf(r1[rr].y, c1.y, dot);
          dot = fmaf(r1[rr].z, c1.z, dot); dot = fmaf(r1[rr].w, c1.w, dot);
#pragma unroll
          for (int off = 1; off < 64; off <<= 1) dot += __shfl_xor(dot, off);
          float sc = cbn_q[k] - 2.f * dot;
          if (sc < bs || (sc == bs && k < bk)) { bs = sc; bk = k; }
        }
      }
      if (lane == 0) idxo[(size_t)qi * NROWS + row0g + row] = (float)bk;
      const f32x4* crow = (const f32x4*)(cb_q + ((size_t)bk << 9)) + lane * 2;
      f32x4 c0 = crow[0], c1 = crow[1];
      r0[rr].x -= c0.x; r0[rr].y -= c0.y; r0[rr].z -= c0.z; r0[rr].w -= c0.w;
      r1[rr].x -= c1.x; r1[rr].y -= c1.y; r1[rr].z -= c1.z; r1[rr].w -= c1.w;
      lsum += r0[rr].x*r0[rr].x + r0[rr].y*r0[rr].y + r0[rr].z*r0[rr].z + r0[rr].w*r0[rr].w
            + r1[rr].x*r1[rr].x + r1[rr].y*r1[rr].y + r1[rr].z*r1[rr].z + r1[rr].w*r1[rr].w;
    }
    __syncthreads();                            // E: step done
  }

  // ---- write quantized_out = x - r_final ----
#pragma unroll
  for (int rr = 0; rr < 8; ++rr) {
    size_t gb = (size_t)(row0g + w * 8 + rr) * Dq + lane * 8;
    f32x4 xv0 = *(const f32x4*)(x + gb), xv1 = *(const f32x4*)(x + gb + 4);
    f32x4 o0, o1;
    o0.x = xv0.x - r0[rr].x; o0.y = xv0.y - r0[rr].y;
    o0.z = xv0.z - r0[rr].z; o0.w = xv0.w - r0[rr].w;
    o1.x = xv1.x - r1[rr].x; o1.y = xv1.y - r1[rr].y;
    o1.z = xv1.z - r1[rr].z; o1.w = xv1.w - r1[rr].w;
    *(f32x4*)(qo + gb) = o0;
    *(f32x4*)(qo + gb + 4) = o1;
  }
#pragma unroll
  for (int off = 1; off < 64; off <<= 1) lsum += __shfl_xor(lsum, off);
  if (lane == 0) atomicAdd(lacc, lsum);
}

// ============ conv1d stride2 SAME via bf16 MFMA + exact GELU ============
__global__ __launch_bounds__(512, 2) void conv_mfma(const float* __restrict__ qo,
                                                    const __bf16* __restrict__ wb,
                                                    float* __restrict__ y) {
  __shared__ char As[259 * 128];                // 259 input rows x 64 ci bf16
  const int tid = threadIdx.x;
  const int w = tid >> 6, lane = tid & 63, l31 = lane & 31, hs = lane >> 5;
  const int rowblk = blockIdx.x, coblk = blockIdx.y;
  const int n = rowblk >> 4;
  const int o0 = (rowblk & 15) * 128;
  const int t0 = 2 * o0 - 1;
  const int c32g = coblk * 8 + w;

  f32x16 acc[4];
#pragma unroll
  for (int rt = 0; rt < 4; ++rt)
#pragma unroll
    for (int i = 0; i < 16; ++i) acc[rt][i] = 0.f;

  for (int ct8 = 0; ct8 < 8; ++ct8) {
    __syncthreads();
    for (int s = tid; s < 2072; s += 512) {
      int irow = s >> 3, cg = s & 7;
      int t = t0 + irow;
      bf16x8 bv;
      if (t >= 0 && t < Tq) {
        const float* src = qo + ((size_t)(n * Tq + t)) * Dq + ct8 * 64 + cg * 8;
        f32x4 v0 = *(const f32x4*)(src), v1 = *(const f32x4*)(src + 4);
        bv[0]=(__bf16)v0.x; bv[1]=(__bf16)v0.y; bv[2]=(__bf16)v0.z; bv[3]=(__bf16)v0.w;
        bv[4]=(__bf16)v1.x; bv[5]=(__bf16)v1.y; bv[6]=(__bf16)v1.z; bv[7]=(__bf16)v1.w;
      } else {
#pragma unroll
        for (int e = 0; e < 8; ++e) bv[e] = (__bf16)0.f;
      }
      *(bf16x8*)(As + ((irow * 128 + cg * 16) ^ (((irow >> 1) & 7) << 4))) = bv;
    }
    __syncthreads();
#pragma unroll
    for (int kw = 0; kw < 5; ++kw) {
#pragma unroll
      for (int ks = 0; ks < 4; ++ks) {
        int s16 = kw * 32 + ct8 * 4 + ks;
        bf16x8 b = *(const bf16x8*)(wb + ((size_t)(s16 * 16 + c32g) * 2 + hs) * 256 + l31 * 8);
#pragma unroll
        for (int rt = 0; rt < 4; ++rt) {
          int ir = 2 * (rt * 32 + l31) + kw;
          bf16x8 a = *(const bf16x8*)(As + ((ir * 128 + ks * 32 + hs * 16) ^ (((ir >> 1) & 7) << 4)));
          acc[rt] = __builtin_amdgcn_mfma_f32_32x32x16_bf16(a, b, acc[rt], 0, 0, 0);
        }
      }
    }
  }
  const int co = coblk * 256 + w * 32 + l31;
#pragma unroll
  for (int rt = 0; rt < 4; ++rt)
#pragma unroll
    for (int i = 0; i < 16; ++i) {
      int orow = rt * 32 + (i & 3) + 8 * (i >> 2) + 4 * hs;
      float v = acc[rt][i];
      float g = 0.5f * v * (1.f + erff(v * 0.70710678118654752f));
      y[((size_t)(n * OWn + o0 + orow)) * Dq + co] = g;
    }
}

__global__ void loss_final(const float* __restrict__ lacc, float* __restrict__ out) {
  out[0] = 0.25f * lacc[0] / 16777216.0f;
}

extern "C" void kernel_launch(void* const* d_in, const int* in_sizes, int n_in,
                              void* d_out, int out_size, void* d_ws, size_t ws_size,
                              hipStream_t stream) {
  const float* x  = (const float*)d_in[0];
  const float* cb = (const float*)d_in[1];
  const float* cw = (const float*)d_in[2];
  float* out = (float*)d_out;
  float* y    = out;
  float* qo   = out + QO_OFF;
  float* idxo = out + IDX_OFF;
  float* losso = out + LOSS_OFF;

  float* fws    = (float*)d_ws;
  float* lacc   = fws;                // 1
  float* cmax   = fws + 8;            // 4
  float* cbnorm = fws + 16;           // 4096
  _Float16* cbf = (_Float16*)((char*)d_ws + (32 << 10));    // 4 MB
  __bf16* wb  = (__bf16*)((char*)d_ws + (8 << 20));         // 2.62 MB

  prep_cb<<<1024, 256, 0, stream>>>(cb, cbnorm, cbf, lacc);
  prep_cmax<<<1, 256, 0, stream>>>(cbnorm, cmax);
  prep_wb<<<640, 256, 0, stream>>>(cw, wb);

  vq_all<<<512, 512, 0, stream>>>(x, qo, cbf, cb, cbnorm, cmax, idxo, lacc);

  conv_mfma<<<dim3(128, 2), 512, 0, stream>>>(qo, wb, y);
  loss_final<<<1, 1, 0, stream>>>(lacc, losso);
}